// Round 10
// baseline (129.445 us; speedup 1.0000x reference)
//
#include <hip/hip_runtime.h>
#include <math.h>

#define BB 64
#define SS 1024
#define DD 32
#define HH 2
#define DHH 16
#define VV 28
#define QSC 0.3606737602222409f   // 0.25 * log2(e)

typedef __attribute__((ext_vector_type(8))) short bf16x8;
typedef __attribute__((ext_vector_type(4))) float f32x4;

__device__ __forceinline__ unsigned pack_hi2(float a, float b) {
    return __builtin_amdgcn_perm(__float_as_uint(b), __float_as_uint(a), 0x07060302u);
}
__device__ __forceinline__ float trunc_hi(float a) {
    return __uint_as_float(__float_as_uint(a) & 0xFFFF0000u);
}
__device__ __forceinline__ unsigned bf_rtne_u(float x) {
    unsigned u = __float_as_uint(x);
    return (u + 0x7FFFu + ((u >> 16) & 1u)) >> 16;
}
__device__ __forceinline__ unsigned pack_rtne2(float a, float b) {
    return bf_rtne_u(a) | (bf_rtne_u(b) << 16);
}
__device__ __forceinline__ bf16x8 as_bf16x8(uint4 u) {
    union { uint4 u; bf16x8 v; } cv; cv.u = u; return cv.v;
}

// Fragment-order layouts. Consumer lane l reads byte l*16.
//  qf[bh][tile(64)][slot(64)][16B]             : Q frags (quads 0,1 hi / 2,3 lo) — used as B operand
//  kf[bh][kch8(8)][piece(g1*4+t)][slot][16B]   : K frags, RTNE bf16, [kh;kh] dup — used as A operand
//  vf[bh][gg(16)][piece(2)][slot(64)][16B]     : V B-frags; piece0 = keys 16*quad+{0..7},
//                                                piece1 = keys 16*quad+{8..15} (quad = slot>>4)
// k_attn_fc: swapped QK^T (mfma(K,Q)) => lane (quad,c) holds P[q=c][key=16*quad+4r+t],
// which is exactly the A-fragment PV needs with the vf key order above. No LDS for P.

// ---------------- kernel 1: MFMA QKV projection -> fragment order; e; W2 ----------
__global__ __launch_bounds__(256) void k_pre(
        const int* __restrict__ x, const float* __restrict__ mask,
        const float* __restrict__ emb, const float* __restrict__ pe,
        const float* __restrict__ wq, const float* __restrict__ bq,
        const float* __restrict__ wk, const float* __restrict__ bk,
        const float* __restrict__ wv, const float* __restrict__ bv,
        const float* __restrict__ wo, const float* __restrict__ bo,
        const float* __restrict__ wfc, const float* __restrict__ bfc,
        int* __restrict__ e, float* __restrict__ W2, float* __restrict__ b2,
        char* __restrict__ qf, char* __restrict__ kf, char* __restrict__ vf) {
    int bid = blockIdx.x;
    int tid = threadIdx.x;
    if (bid < 1024) {
        __shared__ __align__(16) char hbuf[10240];
        __shared__ __align__(16) float Cb[4][16 * 17];
        char* hHi = hbuf;
        char* hLo = hbuf + 5120;
        int wave = tid >> 6, lane = tid & 63;
        int c = lane & 15, kq = lane >> 4;
        {
            int tt = tid >> 2, q4 = tid & 3;
            int idx = bid * 64 + tt;
            int b = idx >> 10, s = idx & 1023;
            float nm = (mask[b * SS + (s >= 3 ? s - 3 : 0)] != 0.0f) ? 1.0f : 0.0f;
            int tok = x[idx];
            float h[8];
#pragma unroll
            for (int i = 0; i < 8; i++)
                h[i] = (emb[tok * DD + q4 * 8 + i] + pe[s * DD + q4 * 8 + i]) * nm;
            unsigned wh[4], wl[4];
#pragma unroll
            for (int wd = 0; wd < 4; wd++) {
                float a0 = h[2 * wd], a1 = h[2 * wd + 1];
                wh[wd] = pack_hi2(a0, a1);
                wl[wd] = pack_hi2(a0 - trunc_hi(a0), a1 - trunc_hi(a1));
            }
            *(uint4*)(hHi + tt * 80 + q4 * 16) = uint4{wh[0], wh[1], wh[2], wh[3]};
            *(uint4*)(hLo + tt * 80 + q4 * 16) = uint4{wl[0], wl[1], wl[2], wl[3]};
        }
        __syncthreads();
        bf16x8 aHh, aHl;
        {
            int off = (wave * 16 + c) * 80 + kq * 16;
            aHh = *(const bf16x8*)(hHi + off);
            aHl = *(const bf16x8*)(hLo + off);
        }
        int blk_b = bid >> 4;
        int s_w = ((bid * 64) & 1023) + wave * 16;   // wave's 16 tokens start
        const f32x4 z4 = {0.0f, 0.0f, 0.0f, 0.0f};
#pragma unroll
        for (int M = 0; M < 3; M++) {
            const float* W    = M == 0 ? wq : (M == 1 ? wk : wv);
            const float* bias = M == 0 ? bq : (M == 1 ? bk : bv);
            bf16x8 Bh[2], Bl[2];
            float bv_[2];
#pragma unroll
            for (int nt = 0; nt < 2; nt++) {
                const float* wrow = W + (nt * 16 + c) * DD + kq * 8;
                float4 wa = ((const float4*)wrow)[0];
                float4 wb = ((const float4*)wrow)[1];
                float f[8] = {wa.x, wa.y, wa.z, wa.w, wb.x, wb.y, wb.z, wb.w};
                unsigned uh[4], ul[4];
#pragma unroll
                for (int wd = 0; wd < 4; wd++) {
                    float a0 = f[2 * wd], a1 = f[2 * wd + 1];
                    uh[wd] = pack_hi2(a0, a1);
                    ul[wd] = pack_hi2(a0 - trunc_hi(a0), a1 - trunc_hi(a1));
                }
                Bh[nt] = as_bf16x8(uint4{uh[0], uh[1], uh[2], uh[3]});
                Bl[nt] = as_bf16x8(uint4{ul[0], ul[1], ul[2], ul[3]});
                bv_[nt] = bias[nt * 16 + c];
            }
#pragma unroll
            for (int nt = 0; nt < 2; nt++) {
                f32x4 acc = __builtin_amdgcn_mfma_f32_16x16x32_bf16(aHh, Bh[nt], z4, 0, 0, 0);
                acc = __builtin_amdgcn_mfma_f32_16x16x32_bf16(aHl, Bh[nt], acc, 0, 0, 0);
                acc = __builtin_amdgcn_mfma_f32_16x16x32_bf16(aHh, Bl[nt], acc, 0, 0, 0);
#pragma unroll
                for (int r = 0; r < 4; r++) {
                    float val = acc[r] + bv_[nt];
                    if (M == 0) val *= QSC;
                    Cb[wave][(kq * 4 + r) * 17 + c] = val;
                }
                int bh = blk_b * 2 + nt;
                if (M == 0) {
                    // Q: exact hi/lo split (quads 0,1 hi; 2,3 lo)
                    int tile = s_w >> 4;
                    int qd = lane >> 4, cc = lane & 15;
                    float f[8];
#pragma unroll
                    for (int j = 0; j < 8; j++) f[j] = Cb[wave][cc * 17 + (qd & 1) * 8 + j];
                    unsigned u[4];
                    if (qd < 2) {
#pragma unroll
                        for (int wd = 0; wd < 4; wd++) u[wd] = pack_hi2(f[2 * wd], f[2 * wd + 1]);
                    } else {
#pragma unroll
                        for (int wd = 0; wd < 4; wd++) {
                            float a0 = f[2 * wd] - trunc_hi(f[2 * wd]);
                            float a1 = f[2 * wd + 1] - trunc_hi(f[2 * wd + 1]);
                            u[wd] = pack_hi2(a0, a1);
                        }
                    }
                    *(uint4*)(qf + ((size_t)((bh << 6) + tile) << 10) + lane * 16)
                        = uint4{u[0], u[1], u[2], u[3]};
                } else if (M == 1) {
                    // K: single RTNE plane, [kh;kh] duplication via qd 0-3
                    int cl = lane & 3, qd = (lane >> 2) & 3, t = lane >> 4;
                    int ch = s_w >> 7, g1 = (s_w >> 6) & 1, c0 = (s_w & 63) >> 2;
                    int keyl = 4 * cl + t;
                    float f[8];
#pragma unroll
                    for (int j = 0; j < 8; j++) f[j] = Cb[wave][keyl * 17 + (qd & 1) * 8 + j];
                    unsigned uh[4];
#pragma unroll
                    for (int wd = 0; wd < 4; wd++) uh[wd] = pack_rtne2(f[2 * wd], f[2 * wd + 1]);
                    char* base = kf + ((size_t)((bh << 3) + ch) << 13)
                               + ((g1 << 2) + t) * 1024 + qd * 256 + (c0 + cl) * 16;
                    *(uint4*)(base) = uint4{uh[0], uh[1], uh[2], uh[3]};
                } else if (lane < 32) {
                    // V: RTNE bf16, vf[bh][gg][piece(=qrel)][slot(Qs*16+dh)]
                    int gg = (s_w >> 6) & 15, Qs = (s_w >> 4) & 3;
                    int qrel = lane >> 4, dh = lane & 15;
                    unsigned u[4];
#pragma unroll
                    for (int wd = 0; wd < 4; wd++) {
                        float f0 = Cb[wave][(qrel * 8 + 2 * wd) * 17 + dh];
                        float f1 = Cb[wave][(qrel * 8 + 2 * wd + 1) * 17 + dh];
                        u[wd] = pack_rtne2(f0, f1);
                    }
                    *(uint4*)(vf + ((size_t)((bh << 5) + (gg << 1) + qrel) << 10)
                              + (Qs * 16 + dh) * 16)
                        = uint4{u[0], u[1], u[2], u[3]};
                }
            }
        }
    } else if (bid < 1088) {
        int b = bid - 1024;
        int lm = -1;
        for (int s = tid; s < SS; s += 256)
            if (mask[b * SS + s] != 0.0f) lm = s;
        __shared__ int red[256];
        red[tid] = lm;
        __syncthreads();
        for (int off = 128; off > 0; off >>= 1) {
            if (tid < off) red[tid] = max(red[tid], red[tid + off]);
            __syncthreads();
        }
        if (tid == 0) {
            int last = red[0];
            int ee = last;
            if (last < SS - 1) ee = min(last + 3, SS - 1);
            e[b] = ee;
        }
    } else {
        for (int t2 = tid; t2 < VV * DD + VV; t2 += 256) {
            if (t2 < VV * DD) {
                int vv = t2 / DD, i = t2 % DD;
                float a = 0.0f;
                for (int j = 0; j < DD; j++) a += wfc[vv * DD + j] * wo[j * DD + i];
                W2[t2] = a;
            } else {
                int vv = t2 - VV * DD;
                float a = bfc[vv];
                for (int j = 0; j < DD; j++) a += wfc[vv * DD + j] * bo[j];
                b2[vv] = a;
            }
        }
    }
}

// ---------------- kernel 2: fused attention + FC, SPLIT-K (2 chunks/tile) + LPT order --------
// grid (64 tiles, 64 y->b via LPT). Block = 1 q-tile x 2 heads x 2 key-chunks (4 waves).
// 16384 waves, each ~ng/2 groups with the round-6 pipeline body (K reg-dbuf, in-step V,
// raw v_exp_f32). Rationale: dur tracks 1/waves across r1/r2/r6/r8 and every throughput
// model sits ~3x below 31us => parallelism-starved latency-bound; split-K doubles
// wave-level parallelism at constant load volume. Max-free softmax => partials combine
// by pure addition (accO_a+accO_b, l_a+l_b) through 5KB LDS. LPT kept (verified, free).

#define LOADK(P0, P1, P2, P3, GN) {                                                \
    int gg_ = (GN) < ge ? (GN) : ge - 1;                                           \
    const char* kg_ = kbase + (size_t)gg_ * 4096;                                  \
    P0 = *(const bf16x8*)(kg_ + lane * 16);                                        \
    P1 = *(const bf16x8*)(kg_ + 1024 + lane * 16);                                 \
    P2 = *(const bf16x8*)(kg_ + 2048 + lane * 16);                                 \
    P3 = *(const bf16x8*)(kg_ + 3072 + lane * 16);                                 \
}

#define STEP(K0, K1, K2, K3, G) {                                                  \
    const char* vg_ = vbase + (size_t)(G) * 2048;                                  \
    bf16x8 v0_ = *(const bf16x8*)(vg_ + lane * 16);                                \
    bf16x8 v1_ = *(const bf16x8*)(vg_ + 1024 + lane * 16);                         \
    f32x4 st[4];                                                                   \
    st[0] = __builtin_amdgcn_mfma_f32_16x16x32_bf16(K0, aQ, z4, 0, 0, 0);          \
    st[1] = __builtin_amdgcn_mfma_f32_16x16x32_bf16(K1, aQ, z4, 0, 0, 0);          \
    st[2] = __builtin_amdgcn_mfma_f32_16x16x32_bf16(K2, aQ, z4, 0, 0, 0);          \
    st[3] = __builtin_amdgcn_mfma_f32_16x16x32_bf16(K3, aQ, z4, 0, 0, 0);          \
    if ((((G) + 1) << 6) > kmax) {                                                 \
        int kb = ((G) << 6) + (quad << 4);                                         \
        _Pragma("unroll")                                                          \
        for (int t = 0; t < 4; t++)                                                \
            _Pragma("unroll")                                                      \
            for (int r = 0; r < 4; r++)                                            \
                if (kb + 4 * r + t >= kmax) st[t][r] = -3e38f;                     \
    }                                                                              \
    float p[4][4];                                                                 \
    _Pragma("unroll")                                                              \
    for (int t = 0; t < 4; t++)                                                    \
        _Pragma("unroll")                                                          \
        for (int r = 0; r < 4; r++) p[t][r] = __builtin_amdgcn_exp2f(st[t][r]);    \
    _Pragma("unroll")                                                              \
    for (int t = 0; t < 4; t++)                                                    \
        l_ += (p[t][0] + p[t][1]) + (p[t][2] + p[t][3]);                           \
    bf16x8 pa0 = as_bf16x8(uint4{pack_hi2(p[0][0], p[1][0]), pack_hi2(p[2][0], p[3][0]), \
                                 pack_hi2(p[0][1], p[1][1]), pack_hi2(p[2][1], p[3][1])}); \
    bf16x8 pa1 = as_bf16x8(uint4{pack_hi2(p[0][2], p[1][2]), pack_hi2(p[2][2], p[3][2]), \
                                 pack_hi2(p[0][3], p[1][3]), pack_hi2(p[2][3], p[3][3])}); \
    accO = __builtin_amdgcn_mfma_f32_16x16x32_bf16(pa0, v0_, accO, 0, 0, 0);       \
    accO = __builtin_amdgcn_mfma_f32_16x16x32_bf16(pa1, v1_, accO, 0, 0, 0);       \
}

__global__ __launch_bounds__(256) void k_attn_fc(
        const char* __restrict__ qf, const char* __restrict__ kf,
        const char* __restrict__ vf, const int* __restrict__ e,
        const float* __restrict__ W2, const float* __restrict__ b2,
        float* __restrict__ out) {
    __shared__ __align__(16) float Ob[16 * 36];
    __shared__ __align__(16) float sW[VV * 36];
    __shared__ float sb[VV];
    __shared__ __align__(16) float accP[4][64][4];
    __shared__ float lP[4][64];
    __shared__ int skey[64];
    __shared__ int smap;
    int tid = threadIdx.x;
    int qt = blockIdx.x;                       // tile 0..63

    for (int i = tid; i < VV * DD; i += 256) sW[(i >> 5) * 36 + (i & 31)] = W2[i];
    if (tid < VV) sb[tid] = b2[tid];
    // LPT rank: key = (ng<<6) | (63-b) is unique per b; rank y = #keys greater.
    if (tid < 64) skey[tid] = ((((e[tid] + 64) >> 6)) << 6) | (63 - tid);
    __syncthreads();
    if (tid < 64) {
        int mykey = skey[tid];
        int cnt = 0;
#pragma unroll
        for (int i = 0; i < 64; i++) cnt += (skey[i] > mykey) ? 1 : 0;
        if (cnt == (int)blockIdx.y) smap = tid;
    }
    __syncthreads();
    int b = smap;

    int kmax = e[b] + 1;
    int ng = (kmax + 63) >> 6;                 // 1..16 live 64-key groups
    int nga = (ng + 1) >> 1;

    int wave = tid >> 6, lane = tid & 63, quad = lane >> 4, c = lane & 15;
    int h = wave & 1, chunk = wave >> 1;
    int gb = chunk ? nga : 0;
    int ge = chunk ? ng : nga;                 // exclusive; ge-gb in {0..8}
    int bh = b * 2 + h;

    const char* kbase = kf + ((size_t)(bh << 3) << 13);   // 64 KB per bh
    const char* vbase = vf + ((size_t)bh << 15);          // 32 KB per bh

    bf16x8 aQ = *(const bf16x8*)(qf + ((size_t)((bh << 6) + qt) << 10) + lane * 16);
    const f32x4 z4 = {0.0f, 0.0f, 0.0f, 0.0f};
    f32x4 accO = z4;
    float l_ = 0.0f;

    if (gb < ge) {
        bf16x8 Ak0, Ak1, Ak2, Ak3, Bk0, Bk1, Bk2, Bk3;
        LOADK(Ak0, Ak1, Ak2, Ak3, gb);
        int g = gb;
        for (; g + 2 <= ge; g += 2) {
            LOADK(Bk0, Bk1, Bk2, Bk3, g + 1);
            STEP(Ak0, Ak1, Ak2, Ak3, g);
            LOADK(Ak0, Ak1, Ak2, Ak3, g + 2);
            STEP(Bk0, Bk1, Bk2, Bk3, g + 1);
        }
        if (g < ge) { STEP(Ak0, Ak1, Ak2, Ak3, g); }
    }

    // per-wave partial: sum quads -> lane holds l(q=c) replicated across quads
    l_ += __shfl_xor(l_, 16);
    l_ += __shfl_xor(l_, 32);

    // publish partials; chunk-0 waves (0,1) combine with chunk-1 (2,3) of same head
    *(f32x4*)&accP[wave][lane][0] = accO;
    lP[wave][lane] = l_;
    __syncthreads();

    if (wave < 2) {
        f32x4 po = *(const f32x4*)&accP[wave + 2][lane][0];
        float lf = l_ + lP[wave + 2][lane];
        // accO[r]+po[r] = O[q=quad*4+r][dh=c] (unnormalized); lf = l(q=c)
        float* obr = Ob + (quad * 4) * 36 + (h << 4) + c;
#pragma unroll
        for (int r = 0; r < 4; r++) {
            float lr = __shfl(lf, (quad << 2) + r, 16);
            obr[r * 36] = (accO[r] + po[r]) * __builtin_amdgcn_rcpf(lr);
        }
    }
    __syncthreads();

    // FC: 16 rows x 28 outputs; 7 of every 16 threads per row produce a float4 of v's
    int rl = tid >> 4, j = tid & 15;
    if (j < 7) {
        const float* orow = Ob + rl * 36;
        float ov[DD];
#pragma unroll
        for (int i = 0; i < DD; i += 4) {
            float4 t4 = *(const float4*)(orow + i);
            ov[i] = t4.x; ov[i + 1] = t4.y; ov[i + 2] = t4.z; ov[i + 3] = t4.w;
        }
        int v0 = j << 2;
        float res[4];
#pragma unroll
        for (int k = 0; k < 4; k++) {
            int vv = v0 + k;
            float a = sb[vv];
#pragma unroll
            for (int d = 0; d < DD; d += 4) {
                float4 w4 = *(const float4*)(sW + vv * 36 + d);
                a += ov[d] * w4.x + ov[d + 1] * w4.y + ov[d + 2] * w4.z + ov[d + 3] * w4.w;
            }
            res[k] = a;
        }
        int q = (qt << 4) + rl;
        size_t off = ((size_t)((b << 10) + q)) * VV + v0;
        *(float4*)(out + off) = float4{res[0], res[1], res[2], res[3]};
    }
}

extern "C" void kernel_launch(void* const* d_in, const int* in_sizes, int n_in,
                              void* d_out, int out_size, void* d_ws, size_t ws_size,
                              hipStream_t stream) {
    const int*   x    = (const int*)d_in[0];
    const float* mask = (const float*)d_in[1];
    const float* emb  = (const float*)d_in[2];
    const float* pe   = (const float*)d_in[3];
    const float* wq   = (const float*)d_in[4];
    const float* bq   = (const float*)d_in[5];
    const float* wk   = (const float*)d_in[6];
    const float* bk   = (const float*)d_in[7];
    const float* wv   = (const float*)d_in[8];
    const float* bv   = (const float*)d_in[9];
    const float* wo   = (const float*)d_in[10];
    const float* bo   = (const float*)d_in[11];
    const float* wfc  = (const float*)d_in[12];
    const float* bfc  = (const float*)d_in[13];
    float* out = (float*)d_out;

    char* ws = (char*)d_ws;
    int*   e  = (int*)ws;                                     // 256 B
    float* W2 = (float*)(ws + 256);
    float* b2 = (float*)(ws + 3840);
    char*  qf = ws + 4096;                                    // 8 MiB  [bh][tile][slot]
    char*  kf = qf + (size_t)8388608;                         // 8 MiB  [bh][kch8][piece][slot]
    char*  vf = kf + (size_t)8388608;                         // 4 MiB  [bh][gg][piece][slot]

    hipLaunchKernelGGL(k_pre, dim3(1089), dim3(256), 0, stream,
                       x, mask, emb, pe, wq, bq, wk, bk, wv, bv, wo, bo, wfc, bfc,
                       e, W2, b2, qf, kf, vf);
    hipLaunchKernelGGL(k_attn_fc, dim3(64, BB), dim3(256), 0, stream,
                       qf, kf, vf, e, W2, b2, out);
}

// Round 12
// 120.307 us; speedup vs baseline: 1.0760x; 1.0760x over previous
//
#include <hip/hip_runtime.h>
#include <math.h>

#define BB 64
#define SS 1024
#define DD 32
#define HH 2
#define DHH 16
#define VV 28
#define QSC 0.3606737602222409f   // 0.25 * log2(e)

typedef __attribute__((ext_vector_type(8))) short bf16x8;
typedef __attribute__((ext_vector_type(4))) float f32x4;

__device__ __forceinline__ unsigned pack_hi2(float a, float b) {
    return __builtin_amdgcn_perm(__float_as_uint(b), __float_as_uint(a), 0x07060302u);
}
__device__ __forceinline__ float trunc_hi(float a) {
    return __uint_as_float(__float_as_uint(a) & 0xFFFF0000u);
}
__device__ __forceinline__ unsigned bf_rtne_u(float x) {
    unsigned u = __float_as_uint(x);
    return (u + 0x7FFFu + ((u >> 16) & 1u)) >> 16;
}
__device__ __forceinline__ unsigned pack_rtne2(float a, float b) {
    return bf_rtne_u(a) | (bf_rtne_u(b) << 16);
}
__device__ __forceinline__ bf16x8 as_bf16x8(uint4 u) {
    union { uint4 u; bf16x8 v; } cv; cv.u = u; return cv.v;
}

// Fragment-order layouts.
//  qf[bh][tile(64)][slot(64)][16B]        : Q frags (quads 0,1 hi / 2,3 lo) — B operand
//  kf[bh][gg(16)][piece(4)][row(16)][dh(16)] bf16, UN-duplicated (32 KB/bh):
//       piece t, row m holds key 4m+t (SAME interleaved semantics as the old duplicated
//       layout — round 11 wrongly stored contiguous tokens per piece). The [kh;kh]
//       duplication for the 16x16x32 A-frag is synthesized at LOAD time: lane (quad,c)
//       reads 16B at row=c, dh-half=(quad&1); lanes quad and quad+2 share bytes.
//       Halves K bytes pulled from L2 per group (4KB->2KB) at identical math/schedule.
//  vf[bh][gg(16)][piece(2)][slot(64)][16B]: V B-frags; piece0 = keys 16*quad+{0..7},
//                                           piece1 = keys 16*quad+{8..15}
// k_attn_fc: swapped QK^T (mfma(K,Q)) => lane (quad,c) holds P[q=c][key=16*quad+4r+t],
// which is exactly the A-fragment PV needs with the vf key order above. No LDS for P.

// ---------------- kernel 1: MFMA QKV projection -> fragment order; e; W2 ----------
__global__ __launch_bounds__(256) void k_pre(
        const int* __restrict__ x, const float* __restrict__ mask,
        const float* __restrict__ emb, const float* __restrict__ pe,
        const float* __restrict__ wq, const float* __restrict__ bq,
        const float* __restrict__ wk, const float* __restrict__ bk,
        const float* __restrict__ wv, const float* __restrict__ bv,
        const float* __restrict__ wo, const float* __restrict__ bo,
        const float* __restrict__ wfc, const float* __restrict__ bfc,
        int* __restrict__ e, float* __restrict__ W2, float* __restrict__ b2,
        char* __restrict__ qf, char* __restrict__ kf, char* __restrict__ vf) {
    int bid = blockIdx.x;
    int tid = threadIdx.x;
    if (bid < 1024) {
        __shared__ __align__(16) char hbuf[10240];
        __shared__ __align__(16) float Cb[4][16 * 17];
        char* hHi = hbuf;
        char* hLo = hbuf + 5120;
        int wave = tid >> 6, lane = tid & 63;
        int c = lane & 15, kq = lane >> 4;
        {
            int tt = tid >> 2, q4 = tid & 3;
            int idx = bid * 64 + tt;
            int b = idx >> 10, s = idx & 1023;
            float nm = (mask[b * SS + (s >= 3 ? s - 3 : 0)] != 0.0f) ? 1.0f : 0.0f;
            int tok = x[idx];
            float h[8];
#pragma unroll
            for (int i = 0; i < 8; i++)
                h[i] = (emb[tok * DD + q4 * 8 + i] + pe[s * DD + q4 * 8 + i]) * nm;
            unsigned wh[4], wl[4];
#pragma unroll
            for (int wd = 0; wd < 4; wd++) {
                float a0 = h[2 * wd], a1 = h[2 * wd + 1];
                wh[wd] = pack_hi2(a0, a1);
                wl[wd] = pack_hi2(a0 - trunc_hi(a0), a1 - trunc_hi(a1));
            }
            *(uint4*)(hHi + tt * 80 + q4 * 16) = uint4{wh[0], wh[1], wh[2], wh[3]};
            *(uint4*)(hLo + tt * 80 + q4 * 16) = uint4{wl[0], wl[1], wl[2], wl[3]};
        }
        __syncthreads();
        bf16x8 aHh, aHl;
        {
            int off = (wave * 16 + c) * 80 + kq * 16;
            aHh = *(const bf16x8*)(hHi + off);
            aHl = *(const bf16x8*)(hLo + off);
        }
        int blk_b = bid >> 4;
        int s_w = ((bid * 64) & 1023) + wave * 16;   // wave's 16 tokens start
        const f32x4 z4 = {0.0f, 0.0f, 0.0f, 0.0f};
#pragma unroll
        for (int M = 0; M < 3; M++) {
            const float* W    = M == 0 ? wq : (M == 1 ? wk : wv);
            const float* bias = M == 0 ? bq : (M == 1 ? bk : bv);
            bf16x8 Bh[2], Bl[2];
            float bv_[2];
#pragma unroll
            for (int nt = 0; nt < 2; nt++) {
                const float* wrow = W + (nt * 16 + c) * DD + kq * 8;
                float4 wa = ((const float4*)wrow)[0];
                float4 wb = ((const float4*)wrow)[1];
                float f[8] = {wa.x, wa.y, wa.z, wa.w, wb.x, wb.y, wb.z, wb.w};
                unsigned uh[4], ul[4];
#pragma unroll
                for (int wd = 0; wd < 4; wd++) {
                    float a0 = f[2 * wd], a1 = f[2 * wd + 1];
                    uh[wd] = pack_hi2(a0, a1);
                    ul[wd] = pack_hi2(a0 - trunc_hi(a0), a1 - trunc_hi(a1));
                }
                Bh[nt] = as_bf16x8(uint4{uh[0], uh[1], uh[2], uh[3]});
                Bl[nt] = as_bf16x8(uint4{ul[0], ul[1], ul[2], ul[3]});
                bv_[nt] = bias[nt * 16 + c];
            }
#pragma unroll
            for (int nt = 0; nt < 2; nt++) {
                f32x4 acc = __builtin_amdgcn_mfma_f32_16x16x32_bf16(aHh, Bh[nt], z4, 0, 0, 0);
                acc = __builtin_amdgcn_mfma_f32_16x16x32_bf16(aHl, Bh[nt], acc, 0, 0, 0);
                acc = __builtin_amdgcn_mfma_f32_16x16x32_bf16(aHh, Bl[nt], acc, 0, 0, 0);
#pragma unroll
                for (int r = 0; r < 4; r++) {
                    float val = acc[r] + bv_[nt];
                    if (M == 0) val *= QSC;
                    Cb[wave][(kq * 4 + r) * 17 + c] = val;
                }
                int bh = blk_b * 2 + nt;
                if (M == 0) {
                    // Q: exact hi/lo split (quads 0,1 hi; 2,3 lo)
                    int tile = s_w >> 4;
                    int qd = lane >> 4, cc = lane & 15;
                    float f[8];
#pragma unroll
                    for (int j = 0; j < 8; j++) f[j] = Cb[wave][cc * 17 + (qd & 1) * 8 + j];
                    unsigned u[4];
                    if (qd < 2) {
#pragma unroll
                        for (int wd = 0; wd < 4; wd++) u[wd] = pack_hi2(f[2 * wd], f[2 * wd + 1]);
                    } else {
#pragma unroll
                        for (int wd = 0; wd < 4; wd++) {
                            float a0 = f[2 * wd] - trunc_hi(f[2 * wd]);
                            float a1 = f[2 * wd + 1] - trunc_hi(f[2 * wd + 1]);
                            u[wd] = pack_hi2(a0, a1);
                        }
                    }
                    *(uint4*)(qf + ((size_t)((bh << 6) + tile) << 10) + lane * 16)
                        = uint4{u[0], u[1], u[2], u[3]};
                } else if (M == 1) {
                    // K: UN-duplicated, interleaved piece semantics: token keyl (global
                    // key-in-group 16*Qs+keyl) -> piece = keyl&3, row = c0 + (keyl>>2)
                    // where c0 = (s_w&63)>>2 = 4*Qs. (Round 11 bug: used contiguous
                    // piece=Qs,row=keyl which mismatched the interleaved consumer.)
                    int keyl = lane >> 2, dq = lane & 3;
                    int gg = (s_w >> 6) & 15, c0 = (s_w & 63) >> 2;
                    float f0 = Cb[wave][keyl * 17 + dq * 4 + 0];
                    float f1 = Cb[wave][keyl * 17 + dq * 4 + 1];
                    float f2 = Cb[wave][keyl * 17 + dq * 4 + 2];
                    float f3 = Cb[wave][keyl * 17 + dq * 4 + 3];
                    *(uint2*)(kf + ((size_t)bh << 15) + gg * 2048 + (keyl & 3) * 512
                              + (c0 + (keyl >> 2)) * 32 + dq * 8)
                        = uint2{pack_rtne2(f0, f1), pack_rtne2(f2, f3)};
                } else if (lane < 32) {
                    // V: RTNE bf16, vf[bh][gg][piece(=qrel)][slot(Qs*16+dh)]
                    int gg = (s_w >> 6) & 15, Qs = (s_w >> 4) & 3;
                    int qrel = lane >> 4, dh = lane & 15;
                    unsigned u[4];
#pragma unroll
                    for (int wd = 0; wd < 4; wd++) {
                        float f0 = Cb[wave][(qrel * 8 + 2 * wd) * 17 + dh];
                        float f1 = Cb[wave][(qrel * 8 + 2 * wd + 1) * 17 + dh];
                        u[wd] = pack_rtne2(f0, f1);
                    }
                    *(uint4*)(vf + ((size_t)((bh << 5) + (gg << 1) + qrel) << 10)
                              + (Qs * 16 + dh) * 16)
                        = uint4{u[0], u[1], u[2], u[3]};
                }
            }
        }
    } else if (bid < 1088) {
        int b = bid - 1024;
        int lm = -1;
        for (int s = tid; s < SS; s += 256)
            if (mask[b * SS + s] != 0.0f) lm = s;
        __shared__ int red[256];
        red[tid] = lm;
        __syncthreads();
        for (int off = 128; off > 0; off >>= 1) {
            if (tid < off) red[tid] = max(red[tid], red[tid + off]);
            __syncthreads();
        }
        if (tid == 0) {
            int last = red[0];
            int ee = last;
            if (last < SS - 1) ee = min(last + 3, SS - 1);
            e[b] = ee;
        }
    } else {
        for (int t2 = tid; t2 < VV * DD + VV; t2 += 256) {
            if (t2 < VV * DD) {
                int vv = t2 / DD, i = t2 % DD;
                float a = 0.0f;
                for (int j = 0; j < DD; j++) a += wfc[vv * DD + j] * wo[j * DD + i];
                W2[t2] = a;
            } else {
                int vv = t2 - VV * DD;
                float a = bfc[vv];
                for (int j = 0; j < DD; j++) a += wfc[vv * DD + j] * bo[j];
                b2[vv] = a;
            }
        }
    }
}

// ---------------- kernel 2: fused attention + FC (round-9 structure, halved K bytes) --------
// grid (32 qt, 64 y->b via LPT). Block = 32 q x 2 heads (4 waves), 2048 blocks, 8192 waves.
// Body = round-6 pipeline (K reg-dbuf, in-step V, raw v_exp_f32). Single change vs round 9:
// kf is un-duplicated; LOADK synthesizes the [kh;kh] A-frag by addressing (lanes quad and
// quad+2 read the same 16B) -> K bytes/group 4KB->2KB. Targets the L2 byte/request rate,
// the one invariant left across all ~31us variants (occupancy/prefetch/order all null).

#define LOADK(P0, P1, P2, P3, GN) {                                                \
    int gg_ = (GN) < ng ? (GN) : ng - 1;                                           \
    const char* kg_ = kbase + (size_t)gg_ * 2048;                                  \
    P0 = *(const bf16x8*)(kg_ + koff);                                             \
    P1 = *(const bf16x8*)(kg_ + 512 + koff);                                       \
    P2 = *(const bf16x8*)(kg_ + 1024 + koff);                                      \
    P3 = *(const bf16x8*)(kg_ + 1536 + koff);                                      \
}

#define STEP(K0, K1, K2, K3, G) {                                                  \
    const char* vg_ = vbase + (size_t)(G) * 2048;                                  \
    bf16x8 v0_ = *(const bf16x8*)(vg_ + lane * 16);                                \
    bf16x8 v1_ = *(const bf16x8*)(vg_ + 1024 + lane * 16);                         \
    f32x4 st[4];                                                                   \
    st[0] = __builtin_amdgcn_mfma_f32_16x16x32_bf16(K0, aQ, z4, 0, 0, 0);          \
    st[1] = __builtin_amdgcn_mfma_f32_16x16x32_bf16(K1, aQ, z4, 0, 0, 0);          \
    st[2] = __builtin_amdgcn_mfma_f32_16x16x32_bf16(K2, aQ, z4, 0, 0, 0);          \
    st[3] = __builtin_amdgcn_mfma_f32_16x16x32_bf16(K3, aQ, z4, 0, 0, 0);          \
    if ((((G) + 1) << 6) > kmax) {                                                 \
        int kb = ((G) << 6) + (quad << 4);                                         \
        _Pragma("unroll")                                                          \
        for (int t = 0; t < 4; t++)                                                \
            _Pragma("unroll")                                                      \
            for (int r = 0; r < 4; r++)                                            \
                if (kb + 4 * r + t >= kmax) st[t][r] = -3e38f;                     \
    }                                                                              \
    float p[4][4];                                                                 \
    _Pragma("unroll")                                                              \
    for (int t = 0; t < 4; t++)                                                    \
        _Pragma("unroll")                                                          \
        for (int r = 0; r < 4; r++) p[t][r] = __builtin_amdgcn_exp2f(st[t][r]);    \
    _Pragma("unroll")                                                              \
    for (int t = 0; t < 4; t++)                                                    \
        l_ += (p[t][0] + p[t][1]) + (p[t][2] + p[t][3]);                           \
    bf16x8 pa0 = as_bf16x8(uint4{pack_hi2(p[0][0], p[1][0]), pack_hi2(p[2][0], p[3][0]), \
                                 pack_hi2(p[0][1], p[1][1]), pack_hi2(p[2][1], p[3][1])}); \
    bf16x8 pa1 = as_bf16x8(uint4{pack_hi2(p[0][2], p[1][2]), pack_hi2(p[2][2], p[3][2]), \
                                 pack_hi2(p[0][3], p[1][3]), pack_hi2(p[2][3], p[3][3])}); \
    accO = __builtin_amdgcn_mfma_f32_16x16x32_bf16(pa0, v0_, accO, 0, 0, 0);       \
    accO = __builtin_amdgcn_mfma_f32_16x16x32_bf16(pa1, v1_, accO, 0, 0, 0);       \
}

__global__ __launch_bounds__(256) void k_attn_fc(
        const char* __restrict__ qf, const char* __restrict__ kf,
        const char* __restrict__ vf, const int* __restrict__ e,
        const float* __restrict__ W2, const float* __restrict__ b2,
        float* __restrict__ out) {
    __shared__ __align__(16) float Ob[32 * 36];
    __shared__ __align__(16) float sW[VV * 36];
    __shared__ float sb[VV];
    __shared__ int skey[64];
    __shared__ int smap;
    int tid = threadIdx.x;
    int qt = blockIdx.x;

    for (int i = tid; i < VV * DD; i += 256) sW[(i >> 5) * 36 + (i & 31)] = W2[i];
    if (tid < VV) sb[tid] = b2[tid];
    // LPT rank: key = (ng<<6) | (63-b) is unique per b; rank y = #keys greater.
    if (tid < 64) skey[tid] = ((((e[tid] + 64) >> 6)) << 6) | (63 - tid);
    __syncthreads();
    if (tid < 64) {
        int mykey = skey[tid];
        int cnt = 0;
#pragma unroll
        for (int i = 0; i < 64; i++) cnt += (skey[i] > mykey) ? 1 : 0;
        if (cnt == (int)blockIdx.y) smap = tid;
    }
    __syncthreads();
    int b = smap;

    int kmax = e[b] + 1;
    int ng = (kmax + 63) >> 6;                 // 1..16 live 64-key groups

    int wave = tid >> 6, lane = tid & 63, quad = lane >> 4, c = lane & 15;
    int h = wave & 1, ts = wave >> 1;
    int tile = (qt << 1) + ts;
    int bh = b * 2 + h;
    int koff = (c << 5) + ((quad & 1) << 4);   // row(=c)*32 + dh-half*16

    const char* kbase = kf + ((size_t)bh << 15);          // 32 KB per bh (un-dup)
    const char* vbase = vf + ((size_t)bh << 15);          // 32 KB per bh

    bf16x8 aQ = *(const bf16x8*)(qf + ((size_t)((bh << 6) + tile) << 10) + lane * 16);
    const f32x4 z4 = {0.0f, 0.0f, 0.0f, 0.0f};
    f32x4 accO = z4;
    float l_ = 0.0f;

    bf16x8 Ak0, Ak1, Ak2, Ak3, Bk0, Bk1, Bk2, Bk3;
    LOADK(Ak0, Ak1, Ak2, Ak3, 0);
    int g = 0;
    for (; g + 2 <= ng; g += 2) {
        LOADK(Bk0, Bk1, Bk2, Bk3, g + 1);
        STEP(Ak0, Ak1, Ak2, Ak3, g);
        LOADK(Ak0, Ak1, Ak2, Ak3, g + 2);
        STEP(Bk0, Bk1, Bk2, Bk3, g + 1);
    }
    if (g < ng) { STEP(Ak0, Ak1, Ak2, Ak3, g); }

    // denominator: sum the 4 quads (lanes +16, +32), then redistribute per q-row
    l_ += __shfl_xor(l_, 16);
    l_ += __shfl_xor(l_, 32);

    // accO[r] = O[q = tile*16 + quad*4 + r][dh = c]; normalize into Ob
    float* obr = Ob + (ts * 16 + quad * 4) * 36 + h * 16 + c;
#pragma unroll
    for (int r = 0; r < 4; r++) {
        float lr = __shfl(l_, (quad << 2) + r, 16);
        obr[r * 36] = accO[r] * __builtin_amdgcn_rcpf(lr);
    }
    __syncthreads();

    // FC: 32 rows x 28 outputs; 7 threads/row each produce a float4 of v's
    int rl = tid >> 3, j = tid & 7;
    if (j < 7) {
        const float* orow = Ob + rl * 36;
        float ov[DD];
#pragma unroll
        for (int i = 0; i < DD; i += 4) {
            float4 t4 = *(const float4*)(orow + i);
            ov[i] = t4.x; ov[i + 1] = t4.y; ov[i + 2] = t4.z; ov[i + 3] = t4.w;
        }
        int v0 = j << 2;
        float res[4];
#pragma unroll
        for (int k = 0; k < 4; k++) {
            int vv = v0 + k;
            float a = sb[vv];
#pragma unroll
            for (int d = 0; d < DD; d += 4) {
                float4 w4 = *(const float4*)(sW + vv * 36 + d);
                a += ov[d] * w4.x + ov[d + 1] * w4.y + ov[d + 2] * w4.z + ov[d + 3] * w4.w;
            }
            res[k] = a;
        }
        int q = (qt << 5) + rl;
        size_t off = ((size_t)((b << 10) + q)) * VV + v0;
        *(float4*)(out + off) = float4{res[0], res[1], res[2], res[3]};
    }
}

extern "C" void kernel_launch(void* const* d_in, const int* in_sizes, int n_in,
                              void* d_out, int out_size, void* d_ws, size_t ws_size,
                              hipStream_t stream) {
    const int*   x    = (const int*)d_in[0];
    const float* mask = (const float*)d_in[1];
    const float* emb  = (const float*)d_in[2];
    const float* pe   = (const float*)d_in[3];
    const float* wq   = (const float*)d_in[4];
    const float* bq   = (const float*)d_in[5];
    const float* wk   = (const float*)d_in[6];
    const float* bk   = (const float*)d_in[7];
    const float* wv   = (const float*)d_in[8];
    const float* bv   = (const float*)d_in[9];
    const float* wo   = (const float*)d_in[10];
    const float* bo   = (const float*)d_in[11];
    const float* wfc  = (const float*)d_in[12];
    const float* bfc  = (const float*)d_in[13];
    float* out = (float*)d_out;

    char* ws = (char*)d_ws;
    int*   e  = (int*)ws;                                     // 256 B
    float* W2 = (float*)(ws + 256);
    float* b2 = (float*)(ws + 3840);
    char*  qf = ws + 4096;                                    // 8 MiB  [bh][tile][slot]
    char*  kf = qf + (size_t)8388608;                         // 4 MiB  [bh][gg][piece][row][dh]
    char*  vf = kf + (size_t)4194304;                         // 4 MiB  [bh][gg][piece][slot]

    hipLaunchKernelGGL(k_pre, dim3(1089), dim3(256), 0, stream,
                       x, mask, emb, pe, wq, bq, wk, bk, wv, bv, wo, bo, wfc, bfc,
                       e, W2, b2, qf, kf, vf);
    hipLaunchKernelGGL(k_attn_fc, dim3(SS / 32, BB), dim3(256), 0, stream,
                       qf, kf, vf, e, W2, b2, out);
}

// Round 13
// 116.653 us; speedup vs baseline: 1.1097x; 1.0313x over previous
//
#include <hip/hip_runtime.h>
#include <math.h>

#define BB 64
#define SS 1024
#define DD 32
#define HH 2
#define DHH 16
#define VV 28
#define QSC 0.3606737602222409f   // 0.25 * log2(e)

typedef __attribute__((ext_vector_type(8))) short bf16x8;
typedef __attribute__((ext_vector_type(4))) float f32x4;

__device__ __forceinline__ unsigned pack_hi2(float a, float b) {
    return __builtin_amdgcn_perm(__float_as_uint(b), __float_as_uint(a), 0x07060302u);
}
__device__ __forceinline__ float trunc_hi(float a) {
    return __uint_as_float(__float_as_uint(a) & 0xFFFF0000u);
}
__device__ __forceinline__ unsigned bf_rtne_u(float x) {
    unsigned u = __float_as_uint(x);
    return (u + 0x7FFFu + ((u >> 16) & 1u)) >> 16;
}
__device__ __forceinline__ unsigned pack_rtne2(float a, float b) {
    return bf_rtne_u(a) | (bf_rtne_u(b) << 16);
}
__device__ __forceinline__ bf16x8 as_bf16x8(uint4 u) {
    union { uint4 u; bf16x8 v; } cv; cv.u = u; return cv.v;
}

// Fragment-order layouts.
//  qf[bh][tile(64)][slot(64)][16B]        : Q frags (quads 0,1 hi / 2,3 lo) — B operand
//  kf[bh][gg(16)][piece(4)][row(16)][dh(16)] bf16, UN-duplicated (32 KB/bh):
//       piece t, row m holds key 4m+t. [kh;kh] duplication synthesized at LOAD:
//       lane (quad,c) reads 16B at row=c, dh-half=(quad&1); lanes quad and quad+2 share.
//  vf[bh][gg(16)][piece(2)][slot(64)][16B]: V B-frags; piece0 = keys 16*quad+{0..7},
//                                           piece1 = keys 16*quad+{8..15}
// k_attn_fc: swapped QK^T (mfma(K,Q)) => lane (quad,c) holds P[q=c][key=16*quad+4r+t],
// which is exactly the A-fragment PV needs with the vf key order above. No LDS for P.

// ---------------- kernel 1: MFMA QKV projection -> fragment order; e; W2 ----------
__global__ __launch_bounds__(256) void k_pre(
        const int* __restrict__ x, const float* __restrict__ mask,
        const float* __restrict__ emb, const float* __restrict__ pe,
        const float* __restrict__ wq, const float* __restrict__ bq,
        const float* __restrict__ wk, const float* __restrict__ bk,
        const float* __restrict__ wv, const float* __restrict__ bv,
        const float* __restrict__ wo, const float* __restrict__ bo,
        const float* __restrict__ wfc, const float* __restrict__ bfc,
        int* __restrict__ e, float* __restrict__ W2, float* __restrict__ b2,
        char* __restrict__ qf, char* __restrict__ kf, char* __restrict__ vf) {
    int bid = blockIdx.x;
    int tid = threadIdx.x;
    if (bid < 1024) {
        __shared__ __align__(16) char hbuf[10240];
        __shared__ __align__(16) float Cb[4][16 * 17];
        char* hHi = hbuf;
        char* hLo = hbuf + 5120;
        int wave = tid >> 6, lane = tid & 63;
        int c = lane & 15, kq = lane >> 4;
        {
            int tt = tid >> 2, q4 = tid & 3;
            int idx = bid * 64 + tt;
            int b = idx >> 10, s = idx & 1023;
            float nm = (mask[b * SS + (s >= 3 ? s - 3 : 0)] != 0.0f) ? 1.0f : 0.0f;
            int tok = x[idx];
            float h[8];
#pragma unroll
            for (int i = 0; i < 8; i++)
                h[i] = (emb[tok * DD + q4 * 8 + i] + pe[s * DD + q4 * 8 + i]) * nm;
            unsigned wh[4], wl[4];
#pragma unroll
            for (int wd = 0; wd < 4; wd++) {
                float a0 = h[2 * wd], a1 = h[2 * wd + 1];
                wh[wd] = pack_hi2(a0, a1);
                wl[wd] = pack_hi2(a0 - trunc_hi(a0), a1 - trunc_hi(a1));
            }
            *(uint4*)(hHi + tt * 80 + q4 * 16) = uint4{wh[0], wh[1], wh[2], wh[3]};
            *(uint4*)(hLo + tt * 80 + q4 * 16) = uint4{wl[0], wl[1], wl[2], wl[3]};
        }
        __syncthreads();
        bf16x8 aHh, aHl;
        {
            int off = (wave * 16 + c) * 80 + kq * 16;
            aHh = *(const bf16x8*)(hHi + off);
            aHl = *(const bf16x8*)(hLo + off);
        }
        int blk_b = bid >> 4;
        int s_w = ((bid * 64) & 1023) + wave * 16;   // wave's 16 tokens start
        const f32x4 z4 = {0.0f, 0.0f, 0.0f, 0.0f};
#pragma unroll
        for (int M = 0; M < 3; M++) {
            const float* W    = M == 0 ? wq : (M == 1 ? wk : wv);
            const float* bias = M == 0 ? bq : (M == 1 ? bk : bv);
            bf16x8 Bh[2], Bl[2];
            float bv_[2];
#pragma unroll
            for (int nt = 0; nt < 2; nt++) {
                const float* wrow = W + (nt * 16 + c) * DD + kq * 8;
                float4 wa = ((const float4*)wrow)[0];
                float4 wb = ((const float4*)wrow)[1];
                float f[8] = {wa.x, wa.y, wa.z, wa.w, wb.x, wb.y, wb.z, wb.w};
                unsigned uh[4], ul[4];
#pragma unroll
                for (int wd = 0; wd < 4; wd++) {
                    float a0 = f[2 * wd], a1 = f[2 * wd + 1];
                    uh[wd] = pack_hi2(a0, a1);
                    ul[wd] = pack_hi2(a0 - trunc_hi(a0), a1 - trunc_hi(a1));
                }
                Bh[nt] = as_bf16x8(uint4{uh[0], uh[1], uh[2], uh[3]});
                Bl[nt] = as_bf16x8(uint4{ul[0], ul[1], ul[2], ul[3]});
                bv_[nt] = bias[nt * 16 + c];
            }
#pragma unroll
            for (int nt = 0; nt < 2; nt++) {
                f32x4 acc = __builtin_amdgcn_mfma_f32_16x16x32_bf16(aHh, Bh[nt], z4, 0, 0, 0);
                acc = __builtin_amdgcn_mfma_f32_16x16x32_bf16(aHl, Bh[nt], acc, 0, 0, 0);
                acc = __builtin_amdgcn_mfma_f32_16x16x32_bf16(aHh, Bl[nt], acc, 0, 0, 0);
#pragma unroll
                for (int r = 0; r < 4; r++) {
                    float val = acc[r] + bv_[nt];
                    if (M == 0) val *= QSC;
                    Cb[wave][(kq * 4 + r) * 17 + c] = val;
                }
                int bh = blk_b * 2 + nt;
                if (M == 0) {
                    // Q: exact hi/lo split (quads 0,1 hi; 2,3 lo)
                    int tile = s_w >> 4;
                    int qd = lane >> 4, cc = lane & 15;
                    float f[8];
#pragma unroll
                    for (int j = 0; j < 8; j++) f[j] = Cb[wave][cc * 17 + (qd & 1) * 8 + j];
                    unsigned u[4];
                    if (qd < 2) {
#pragma unroll
                        for (int wd = 0; wd < 4; wd++) u[wd] = pack_hi2(f[2 * wd], f[2 * wd + 1]);
                    } else {
#pragma unroll
                        for (int wd = 0; wd < 4; wd++) {
                            float a0 = f[2 * wd] - trunc_hi(f[2 * wd]);
                            float a1 = f[2 * wd + 1] - trunc_hi(f[2 * wd + 1]);
                            u[wd] = pack_hi2(a0, a1);
                        }
                    }
                    *(uint4*)(qf + ((size_t)((bh << 6) + tile) << 10) + lane * 16)
                        = uint4{u[0], u[1], u[2], u[3]};
                } else if (M == 1) {
                    // K: UN-duplicated, interleaved piece semantics: token keyl ->
                    // piece = keyl&3, row = c0 + (keyl>>2), c0 = (s_w&63)>>2.
                    int keyl = lane >> 2, dq = lane & 3;
                    int gg = (s_w >> 6) & 15, c0 = (s_w & 63) >> 2;
                    float f0 = Cb[wave][keyl * 17 + dq * 4 + 0];
                    float f1 = Cb[wave][keyl * 17 + dq * 4 + 1];
                    float f2 = Cb[wave][keyl * 17 + dq * 4 + 2];
                    float f3 = Cb[wave][keyl * 17 + dq * 4 + 3];
                    *(uint2*)(kf + ((size_t)bh << 15) + gg * 2048 + (keyl & 3) * 512
                              + (c0 + (keyl >> 2)) * 32 + dq * 8)
                        = uint2{pack_rtne2(f0, f1), pack_rtne2(f2, f3)};
                } else if (lane < 32) {
                    // V: RTNE bf16, vf[bh][gg][piece(=qrel)][slot(Qs*16+dh)]
                    int gg = (s_w >> 6) & 15, Qs = (s_w >> 4) & 3;
                    int qrel = lane >> 4, dh = lane & 15;
                    unsigned u[4];
#pragma unroll
                    for (int wd = 0; wd < 4; wd++) {
                        float f0 = Cb[wave][(qrel * 8 + 2 * wd) * 17 + dh];
                        float f1 = Cb[wave][(qrel * 8 + 2 * wd + 1) * 17 + dh];
                        u[wd] = pack_rtne2(f0, f1);
                    }
                    *(uint4*)(vf + ((size_t)((bh << 5) + (gg << 1) + qrel) << 10)
                              + (Qs * 16 + dh) * 16)
                        = uint4{u[0], u[1], u[2], u[3]};
                }
            }
        }
    } else if (bid < 1088) {
        int b = bid - 1024;
        int lm = -1;
        for (int s = tid; s < SS; s += 256)
            if (mask[b * SS + s] != 0.0f) lm = s;
        __shared__ int red[256];
        red[tid] = lm;
        __syncthreads();
        for (int off = 128; off > 0; off >>= 1) {
            if (tid < off) red[tid] = max(red[tid], red[tid + off]);
            __syncthreads();
        }
        if (tid == 0) {
            int last = red[0];
            int ee = last;
            if (last < SS - 1) ee = min(last + 3, SS - 1);
            e[b] = ee;
        }
    } else {
        for (int t2 = tid; t2 < VV * DD + VV; t2 += 256) {
            if (t2 < VV * DD) {
                int vv = t2 / DD, i = t2 % DD;
                float a = 0.0f;
                for (int j = 0; j < DD; j++) a += wfc[vv * DD + j] * wo[j * DD + i];
                W2[t2] = a;
            } else {
                int vv = t2 - VV * DD;
                float a = bfc[vv];
                for (int j = 0; j < DD; j++) a += wfc[vv * DD + j] * bo[j];
                b2[vv] = a;
            }
        }
    }
}

// ---------------- kernel 2: fused attention + FC, DEEP (2-step-ahead) K+V prefetch ----------
// grid (32 qt, 64 y->b via LPT). Block = 32 q x 2 heads (4 waves), 2048 blocks, 8192 waves.
// Theory: K/V (~16MB) live in L3, not any XCD's 4MB L2 -> per-step loads are ~600-900cy
// L3 hits vs ~200cy step compute. All depth-1 prefetch variants (r6/r7) hide only ~1 step
// (and the compiler already achieves ~that on every variant -> the nulls). Three-buffer
// circular pipeline issues LOADKV(g+2) before consuming step g: lookahead ~2.5 steps.
// Cost: ~+50 VGPR (3 waves/SIMD) -- per-wave stall drops from ~75% to ~30%, net win
// per the 8192x8.5x800cy/1024SIMD ~ 28us model that finally fits ALL null results.
// WRITE_SIZE must stay ~7MB (no scratch -- r3 tripwire).

#define LOADKV(K0, K1, K2, K3, V0, V1, GN) {                                       \
    int gg_ = (GN) < ng ? (GN) : ng - 1;                                           \
    const char* kg_ = kbase + (size_t)gg_ * 2048;                                  \
    const char* vg_ = vbase + (size_t)gg_ * 2048;                                  \
    K0 = *(const bf16x8*)(kg_ + koff);                                             \
    K1 = *(const bf16x8*)(kg_ + 512 + koff);                                       \
    K2 = *(const bf16x8*)(kg_ + 1024 + koff);                                      \
    K3 = *(const bf16x8*)(kg_ + 1536 + koff);                                      \
    V0 = *(const bf16x8*)(vg_ + lane * 16);                                        \
    V1 = *(const bf16x8*)(vg_ + 1024 + lane * 16);                                 \
}

#define STEP(K0, K1, K2, K3, V0, V1, G) {                                          \
    f32x4 st[4];                                                                   \
    st[0] = __builtin_amdgcn_mfma_f32_16x16x32_bf16(K0, aQ, z4, 0, 0, 0);          \
    st[1] = __builtin_amdgcn_mfma_f32_16x16x32_bf16(K1, aQ, z4, 0, 0, 0);          \
    st[2] = __builtin_amdgcn_mfma_f32_16x16x32_bf16(K2, aQ, z4, 0, 0, 0);          \
    st[3] = __builtin_amdgcn_mfma_f32_16x16x32_bf16(K3, aQ, z4, 0, 0, 0);          \
    if ((((G) + 1) << 6) > kmax) {                                                 \
        int kb = ((G) << 6) + (quad << 4);                                         \
        _Pragma("unroll")                                                          \
        for (int t = 0; t < 4; t++)                                                \
            _Pragma("unroll")                                                      \
            for (int r = 0; r < 4; r++)                                            \
                if (kb + 4 * r + t >= kmax) st[t][r] = -3e38f;                     \
    }                                                                              \
    float p[4][4];                                                                 \
    _Pragma("unroll")                                                              \
    for (int t = 0; t < 4; t++)                                                    \
        _Pragma("unroll")                                                          \
        for (int r = 0; r < 4; r++) p[t][r] = __builtin_amdgcn_exp2f(st[t][r]);    \
    _Pragma("unroll")                                                              \
    for (int t = 0; t < 4; t++)                                                    \
        l_ += (p[t][0] + p[t][1]) + (p[t][2] + p[t][3]);                           \
    bf16x8 pa0 = as_bf16x8(uint4{pack_hi2(p[0][0], p[1][0]), pack_hi2(p[2][0], p[3][0]), \
                                 pack_hi2(p[0][1], p[1][1]), pack_hi2(p[2][1], p[3][1])}); \
    bf16x8 pa1 = as_bf16x8(uint4{pack_hi2(p[0][2], p[1][2]), pack_hi2(p[2][2], p[3][2]), \
                                 pack_hi2(p[0][3], p[1][3]), pack_hi2(p[2][3], p[3][3])}); \
    accO = __builtin_amdgcn_mfma_f32_16x16x32_bf16(pa0, V0, accO, 0, 0, 0);        \
    accO = __builtin_amdgcn_mfma_f32_16x16x32_bf16(pa1, V1, accO, 0, 0, 0);        \
}

__global__ __launch_bounds__(256) void k_attn_fc(
        const char* __restrict__ qf, const char* __restrict__ kf,
        const char* __restrict__ vf, const int* __restrict__ e,
        const float* __restrict__ W2, const float* __restrict__ b2,
        float* __restrict__ out) {
    __shared__ __align__(16) float Ob[32 * 36];
    __shared__ __align__(16) float sW[VV * 36];
    __shared__ float sb[VV];
    __shared__ int skey[64];
    __shared__ int smap;
    int tid = threadIdx.x;
    int qt = blockIdx.x;

    for (int i = tid; i < VV * DD; i += 256) sW[(i >> 5) * 36 + (i & 31)] = W2[i];
    if (tid < VV) sb[tid] = b2[tid];
    // LPT rank: key = (ng<<6) | (63-b) is unique per b; rank y = #keys greater.
    if (tid < 64) skey[tid] = ((((e[tid] + 64) >> 6)) << 6) | (63 - tid);
    __syncthreads();
    if (tid < 64) {
        int mykey = skey[tid];
        int cnt = 0;
#pragma unroll
        for (int i = 0; i < 64; i++) cnt += (skey[i] > mykey) ? 1 : 0;
        if (cnt == (int)blockIdx.y) smap = tid;
    }
    __syncthreads();
    int b = smap;

    int kmax = e[b] + 1;
    int ng = (kmax + 63) >> 6;                 // 1..16 live 64-key groups

    int wave = tid >> 6, lane = tid & 63, quad = lane >> 4, c = lane & 15;
    int h = wave & 1, ts = wave >> 1;
    int tile = (qt << 1) + ts;
    int bh = b * 2 + h;
    int koff = (c << 5) + ((quad & 1) << 4);   // row(=c)*32 + dh-half*16

    const char* kbase = kf + ((size_t)bh << 15);          // 32 KB per bh (un-dup)
    const char* vbase = vf + ((size_t)bh << 15);          // 32 KB per bh

    bf16x8 aQ = *(const bf16x8*)(qf + ((size_t)((bh << 6) + tile) << 10) + lane * 16);
    const f32x4 z4 = {0.0f, 0.0f, 0.0f, 0.0f};
    f32x4 accO = z4;
    float l_ = 0.0f;

    bf16x8 Ak0, Ak1, Ak2, Ak3, Av0, Av1;
    bf16x8 Bk0, Bk1, Bk2, Bk3, Bv0, Bv1;
    bf16x8 Ck0, Ck1, Ck2, Ck3, Cv0, Cv1;
    LOADKV(Ak0, Ak1, Ak2, Ak3, Av0, Av1, 0);
    LOADKV(Bk0, Bk1, Bk2, Bk3, Bv0, Bv1, 1);
    int g = 0;
    for (; g + 3 <= ng; g += 3) {
        LOADKV(Ck0, Ck1, Ck2, Ck3, Cv0, Cv1, g + 2);
        STEP(Ak0, Ak1, Ak2, Ak3, Av0, Av1, g);
        LOADKV(Ak0, Ak1, Ak2, Ak3, Av0, Av1, g + 3);
        STEP(Bk0, Bk1, Bk2, Bk3, Bv0, Bv1, g + 1);
        LOADKV(Bk0, Bk1, Bk2, Bk3, Bv0, Bv1, g + 4);
        STEP(Ck0, Ck1, Ck2, Ck3, Cv0, Cv1, g + 2);
    }
    if (g < ng)     { STEP(Ak0, Ak1, Ak2, Ak3, Av0, Av1, g); }
    if (g + 1 < ng) { STEP(Bk0, Bk1, Bk2, Bk3, Bv0, Bv1, g + 1); }

    // denominator: sum the 4 quads (lanes +16, +32), then redistribute per q-row
    l_ += __shfl_xor(l_, 16);
    l_ += __shfl_xor(l_, 32);

    // accO[r] = O[q = tile*16 + quad*4 + r][dh = c]; normalize into Ob
    float* obr = Ob + (ts * 16 + quad * 4) * 36 + h * 16 + c;
#pragma unroll
    for (int r = 0; r < 4; r++) {
        float lr = __shfl(l_, (quad << 2) + r, 16);
        obr[r * 36] = accO[r] * __builtin_amdgcn_rcpf(lr);
    }
    __syncthreads();

    // FC: 32 rows x 28 outputs; 7 threads/row each produce a float4 of v's
    int rl = tid >> 3, j = tid & 7;
    if (j < 7) {
        const float* orow = Ob + rl * 36;
        float ov[DD];
#pragma unroll
        for (int i = 0; i < DD; i += 4) {
            float4 t4 = *(const float4*)(orow + i);
            ov[i] = t4.x; ov[i + 1] = t4.y; ov[i + 2] = t4.z; ov[i + 3] = t4.w;
        }
        int v0 = j << 2;
        float res[4];
#pragma unroll
        for (int k = 0; k < 4; k++) {
            int vv = v0 + k;
            float a = sb[vv];
#pragma unroll
            for (int d = 0; d < DD; d += 4) {
                float4 w4 = *(const float4*)(sW + vv * 36 + d);
                a += ov[d] * w4.x + ov[d + 1] * w4.y + ov[d + 2] * w4.z + ov[d + 3] * w4.w;
            }
            res[k] = a;
        }
        int q = (qt << 5) + rl;
        size_t off = ((size_t)((b << 10) + q)) * VV + v0;
        *(float4*)(out + off) = float4{res[0], res[1], res[2], res[3]};
    }
}

extern "C" void kernel_launch(void* const* d_in, const int* in_sizes, int n_in,
                              void* d_out, int out_size, void* d_ws, size_t ws_size,
                              hipStream_t stream) {
    const int*   x    = (const int*)d_in[0];
    const float* mask = (const float*)d_in[1];
    const float* emb  = (const float*)d_in[2];
    const float* pe   = (const float*)d_in[3];
    const float* wq   = (const float*)d_in[4];
    const float* bq   = (const float*)d_in[5];
    const float* wk   = (const float*)d_in[6];
    const float* bk   = (const float*)d_in[7];
    const float* wv   = (const float*)d_in[8];
    const float* bv   = (const float*)d_in[9];
    const float* wo   = (const float*)d_in[10];
    const float* bo   = (const float*)d_in[11];
    const float* wfc  = (const float*)d_in[12];
    const float* bfc  = (const float*)d_in[13];
    float* out = (float*)d_out;

    char* ws = (char*)d_ws;
    int*   e  = (int*)ws;                                     // 256 B
    float* W2 = (float*)(ws + 256);
    float* b2 = (float*)(ws + 3840);
    char*  qf = ws + 4096;                                    // 8 MiB  [bh][tile][slot]
    char*  kf = qf + (size_t)8388608;                         // 4 MiB  [bh][gg][piece][row][dh]
    char*  vf = kf + (size_t)4194304;                         // 4 MiB  [bh][gg][piece][slot]

    hipLaunchKernelGGL(k_pre, dim3(1089), dim3(256), 0, stream,
                       x, mask, emb, pe, wq, bq, wk, bk, wv, bv, wo, bo, wfc, bfc,
                       e, W2, b2, qf, kf, vf);
    hipLaunchKernelGGL(k_attn_fc, dim3(SS / 32, BB), dim3(256), 0, stream,
                       qf, kf, vf, e, W2, b2, out);
}